// Round 6
// baseline (107.564 us; speedup 1.0000x reference)
//
#include <hip/hip_runtime.h>

#define USER_NUM 100000
#define ITEM_NUM 50000
#define HIDDEN   64
#define BATCH    16384
#define KNB      50
#define NPAIRS   (BATCH * KNB)     // 819200
#define CAP      16                // bucket capacity per user row (Poisson mean 8.2)

#define PAIR_BLOCKS  (NPAIRS / 256)        // 3200
#define LOCLC_BLOCKS (BATCH / 16)          // 1024 (16 elems/block: 4 waves x 4 groups)
#define K3_ROWBLKS   (USER_NUM / 16)       // 6250 (16 rows/block)
#define K3_OVFBLKS   256
#define K3_BLOCKS    (K3_ROWBLKS + K3_OVFBLKS)

// ---- ws layout (bytes) ----
#define OVF_CNT_OFF   0u            // u32
#define COUNTS_OFF    256u          // u32[USER_NUM]  (memset covers both)
#define BUCKETS_OFF   (1u << 19)    // uint2[USER_NUM * CAP] = 12.8 MB
#define OVERFLOW_OFF  (1u << 24)    // uint4[NPAIRS] = 13.1 MB (full capacity: always correct)
#define PARTIAL1_OFF  (1u << 25)    // float[LOCLC_BLOCKS]
#define PARTIAL2_OFF  ((1u << 25) + 8192u)  // float[K3_BLOCKS]

typedef float  f4 __attribute__((ext_vector_type(4)));

__device__ __forceinline__ float log_sigmoid(float x) {
    return fminf(x, 0.0f) - __logf(1.0f + __expf(-fabsf(x)));
}

__device__ __forceinline__ float dot4(f4 a, f4 b) {
    return a[0] * b[0] + a[1] * b[1] + a[2] * b[2] + a[3] * b[3];
}

__device__ __forceinline__ float red16(float v) {
    v += __shfl_xor(v, 1);
    v += __shfl_xor(v, 2);
    v += __shfl_xor(v, 4);
    v += __shfl_xor(v, 8);
    return v;
}

// K1: bucket build (blocks [0,3200)) + LO/LC forward part (blocks [3200,4224))
__global__ __launch_bounds__(256) void k_build(
    const int*   __restrict__ user,
    const int*   __restrict__ pos,
    const int*   __restrict__ neg,
    const float* __restrict__ pos_beta,
    const float* __restrict__ neg_beta,
    const float* __restrict__ weights,
    const int*   __restrict__ neighbor,
    const float* __restrict__ embs,
    char*        __restrict__ ws)
{
    unsigned* counts   = (unsigned*)(ws + COUNTS_OFF);
    unsigned* ovf_cnt  = (unsigned*)(ws + OVF_CNT_OFF);
    uint2*    buckets  = (uint2*)   (ws + BUCKETS_OFF);
    uint4*    overflow = (uint4*)   (ws + OVERFLOW_OFF);
    float*    partial1 = (float*)   (ws + PARTIAL1_OFF);

    const int bid = blockIdx.x;
    if (bid < PAIR_BLOCKS) {
        const int idx  = bid * 256 + threadIdx.x;   // pair id
        const int i    = idx / KNB;                  // compiler magic-div
        const int k    = idx - i * KNB;
        const int item = pos[i] - USER_NUM;
        const int nb   = neighbor[item * KNB + k];
        const float w  = weights[item * KNB + k];
        const unsigned uid = (unsigned)user[i];
        const unsigned slot = atomicAdd(&counts[nb], 1u);   // relaxed device atomic, no fence
        if (slot < CAP) {
            buckets[nb * CAP + slot] = make_uint2(uid, __float_as_uint(w));
        } else {
            const unsigned o = atomicAdd(ovf_cnt, 1u);
            overflow[o] = make_uint4((unsigned)nb, uid, __float_as_uint(w), 0u);
        }
        return;
    }

    // ---- LO/LC: one 16-lane group per batch element ----
    const int lbid = bid - PAIR_BLOCKS;
    const int tid  = threadIdx.x;
    const int wave = tid >> 6;
    const int lane = tid & 63;
    const int g    = lane >> 4;
    const int gl   = lane & 15;
    const int i    = lbid * 16 + wave * 4 + g;

    const char* eb = (const char*)embs;
    const unsigned goff = (unsigned)(gl << 4);

    const int u = user[i];
    const int p = pos[i];
    const int n = neg[i];

    const f4 u4 = *(const f4*)(eb + (unsigned)u * 256u + goff);
    const f4 p4 = *(const f4*)(eb + (unsigned)p * 256u + goff);
    const f4 n4 = *(const f4*)(eb + (unsigned)n * 256u + goff);

    const float pl = red16(dot4(u4, p4));
    const float nl = red16(dot4(u4, n4));

    const float pb  = pos_beta[i];
    const float nbt = neg_beta[i];
    float contrib = -(1.0f + pb)  * log_sigmoid(pl)
                  - (1.0f + nbt) * log_sigmoid(-nl);
    contrib += __shfl_xor(contrib, 16);
    contrib += __shfl_xor(contrib, 32);

    __shared__ float s[4];
    if (lane == 0) s[wave] = contrib;
    __syncthreads();
    if (tid == 0) partial1[lbid] = s[0] + s[1] + s[2] + s[3];
}

// K3: inverted harvest. blocks [0,6250): 16 user rows each; blocks [6250,6506): overflow
__global__ __launch_bounds__(256) void k_harvest(
    const int*   __restrict__ user,     // unused, kept for symmetry
    const float* __restrict__ embs,
    const char*  __restrict__ ws,
    float*       __restrict__ partial2)
{
    const unsigned* counts   = (const unsigned*)(ws + COUNTS_OFF);
    const unsigned* ovf_cnt  = (const unsigned*)(ws + OVF_CNT_OFF);
    const uint2*    buckets  = (const uint2*)   (ws + BUCKETS_OFF);
    const uint4*    overflow = (const uint4*)   (ws + OVERFLOW_OFF);

    const int tid  = threadIdx.x;
    const int wave = tid >> 6;
    const int lane = tid & 63;
    const int g    = lane >> 4;
    const int gl   = lane & 15;
    const unsigned goff = (unsigned)(gl << 4);
    const int base = lane & 48;           // group base lane

    const char* eb = (const char*)embs;
    float acc = 0.0f;

    if (blockIdx.x < K3_ROWBLKS) {
        const int r = blockIdx.x * 16 + wave * 4 + g;    // user row 0..99999
        const unsigned cnt  = counts[r];
        const unsigned cntC = cnt < CAP ? cnt : CAP;
        // this lane's bucket entry (coalesced 128B per group; garbage beyond cnt never used)
        const uint2 be = buckets[r * CAP + gl];

        if (cntC) {
            // stream the neighbor row nontemporally: don't evict hot uid rows from L2
            const f4 e4 = __builtin_nontemporal_load((const f4*)(eb + (unsigned)r * 256u + goff));
            for (unsigned c = 0; c < cntC; c += 4) {
                unsigned uidj[4]; float wj[4];
#pragma unroll
                for (int j = 0; j < 4; ++j) {
                    const unsigned cc  = c + (unsigned)j;
                    const int      src = base + (int)(cc & 15u);
                    const unsigned uu  = (unsigned)__shfl((int)be.x, src);
                    const unsigned wb  = (unsigned)__shfl((int)be.y, src);
                    const bool     v   = cc < cntC;
                    uidj[j] = v ? uu : 0u;                      // dummy -> row 0
                    wj[j]   = v ? __uint_as_float(wb) : 0.0f;   // weight 0 kills dummy
                }
                // 4 independent gathers in flight (footprint: 16384 rows = 4.2 MB, L2-resident)
                const f4 a0 = *(const f4*)(eb + uidj[0] * 256u + goff);
                const f4 a1 = *(const f4*)(eb + uidj[1] * 256u + goff);
                const f4 a2 = *(const f4*)(eb + uidj[2] * 256u + goff);
                const f4 a3 = *(const f4*)(eb + uidj[3] * 256u + goff);
                float d0 = red16(dot4(a0, e4));
                float d1 = red16(dot4(a1, e4));
                float d2 = red16(dot4(a2, e4));
                float d3 = red16(dot4(a3, e4));
                acc += wj[0] * (-log_sigmoid(d0));
                acc += wj[1] * (-log_sigmoid(d1));
                acc += wj[2] * (-log_sigmoid(d2));
                acc += wj[3] * (-log_sigmoid(d3));
            }
        }
    } else {
        // overflow pairs (expected ~1e3 of 819200)
        const unsigned total = *ovf_cnt;
        const int ob   = blockIdx.x - K3_ROWBLKS;
        const unsigned gidx = (unsigned)(ob * 16 + wave * 4 + g);
        for (unsigned e = gidx; e < total; e += K3_OVFBLKS * 16u) {
            const uint4 ov = overflow[e];
            const f4 e4 = *(const f4*)(eb + ov.x * 256u + goff);
            const f4 a4 = *(const f4*)(eb + ov.y * 256u + goff);
            const float d = red16(dot4(a4, e4));
            acc += __uint_as_float(ov.z) * (-log_sigmoid(d));
        }
    }

    acc += __shfl_xor(acc, 16);
    acc += __shfl_xor(acc, 32);
    __shared__ float s[4];
    if (lane == 0) s[wave] = acc;
    __syncthreads();
    if (tid == 0) partial2[blockIdx.x] = 2.5f * (s[0] + s[1] + s[2] + s[3]);
}

__global__ __launch_bounds__(256) void k_final(
    const float* __restrict__ partial1,
    const float* __restrict__ partial2,
    float*       __restrict__ out)
{
    const int tid  = threadIdx.x;
    const int lane = tid & 63;
    const int wave = tid >> 6;

    float s = 0.0f;
    for (int i = tid; i < LOCLC_BLOCKS; i += 256) s += partial1[i];
    for (int i = tid; i < K3_BLOCKS;   i += 256) s += partial2[i];

    s += __shfl_xor(s, 1);
    s += __shfl_xor(s, 2);
    s += __shfl_xor(s, 4);
    s += __shfl_xor(s, 8);
    s += __shfl_xor(s, 16);
    s += __shfl_xor(s, 32);

    __shared__ float ws_[4];
    if (lane == 0) ws_[wave] = s;
    __syncthreads();
    if (tid == 0) out[0] = ws_[0] + ws_[1] + ws_[2] + ws_[3];
}

extern "C" void kernel_launch(void* const* d_in, const int* in_sizes, int n_in,
                              void* d_out, int out_size, void* d_ws, size_t ws_size,
                              hipStream_t stream)
{
    const int*   user     = (const int*)  d_in[0];
    const int*   pos      = (const int*)  d_in[1];
    const int*   neg      = (const int*)  d_in[2];
    const float* pos_beta = (const float*)d_in[3];
    const float* neg_beta = (const float*)d_in[4];
    const float* weights  = (const float*)d_in[5];
    const int*   neighbor = (const int*)  d_in[6];
    const float* embs     = (const float*)d_in[7];

    char* ws = (char*)d_ws;

    // zero ovf counter + counts (covers [0, 512KB))
    hipMemsetAsync(ws, 0, COUNTS_OFF + USER_NUM * sizeof(unsigned), stream);

    k_build<<<PAIR_BLOCKS + LOCLC_BLOCKS, 256, 0, stream>>>(
        user, pos, neg, pos_beta, neg_beta, weights, neighbor, embs, ws);

    k_harvest<<<K3_BLOCKS, 256, 0, stream>>>(
        user, embs, ws, (float*)(ws + PARTIAL2_OFF));

    k_final<<<1, 256, 0, stream>>>(
        (const float*)(ws + PARTIAL1_OFF), (const float*)(ws + PARTIAL2_OFF),
        (float*)d_out);
}

// Round 7
// 36.984 us; speedup vs baseline: 2.9084x; 2.9084x over previous
//
#include <hip/hip_runtime.h>

#define USER_NUM 100000
#define ITEM_NUM 50000
#define HIDDEN   64
#define BATCH    16384
#define KNB      50

// fast, numerically stable log-sigmoid: min(x,0) - log(1 + exp(-|x|))
__device__ __forceinline__ float log_sigmoid(float x) {
    return fminf(x, 0.0f) - __logf(1.0f + __expf(-fabsf(x)));
}

__device__ __forceinline__ float dot4(float4 a, float4 b) {
    return a.x * b.x + a.y * b.y + a.z * b.z + a.w * b.w;
}

// butterfly sum over the 16-lane group (masks 1,2,4,8 stay within group)
__device__ __forceinline__ float red16(float v) {
    v += __shfl_xor(v, 1);
    v += __shfl_xor(v, 2);
    v += __shfl_xor(v, 4);
    v += __shfl_xor(v, 8);
    return v;
}

// One wave per batch element; 4 groups of 16 lanes; each lane holds one
// float4 of the 64-dim row. All 13 neighbor gathers batched up front for MLP.
// Measured (R2/R4/R5 rocprof): ~100 MB L2-miss traffic @ ~3 TB/s on the
// L3/fabric path; logical 222 MB @ 6.7 TB/s == streaming ceiling. Occupancy
// doubling (R5) = null -> pattern-bound, not concurrency-bound.
// DO NOT add per-block fences (R3: 7.4x) or same-address atomics (R4: 2x).
__global__ __launch_bounds__(256) void ultragcn_main(
    const int*   __restrict__ user,
    const int*   __restrict__ pos,
    const int*   __restrict__ neg,
    const float* __restrict__ pos_beta,
    const float* __restrict__ neg_beta,
    const float* __restrict__ weights,
    const int*   __restrict__ neighbor,
    const float* __restrict__ embs,
    float*       __restrict__ partial)
{
    const int tid  = threadIdx.x;
    const int wave = tid >> 6;       // 0..3
    const int lane = tid & 63;
    const int i    = blockIdx.x * 4 + wave;   // batch element (4096*4 = 16384)

    const int g  = lane >> 4;        // group 0..3 within wave
    const int gl = lane & 15;        // lane within group
    const unsigned goff = (unsigned)(gl << 4);   // byte offset within a 256 B row

    const int u = user[i];
    const int p = pos[i];
    const int n = neg[i];
    const int item = p - USER_NUM;

    // index/weight loads first; their latency overlaps the row loads
    int   nbv = 0;
    float wv  = 0.0f;
    if (lane < KNB) {
        nbv = neighbor[item * KNB + lane];
        wv  = weights[item * KNB + lane];
    }

    const char* embsb = (const char*)embs;   // rows are 256 B; table 38.4 MB -> u32 offsets

    const float4 u4 = *(const float4*)(embsb + (unsigned)u * 256u + goff);
    const float4 p4 = *(const float4*)(embsb + (unsigned)p * 256u + goff);
    const float4 n4 = *(const float4*)(embsb + (unsigned)n * 256u + goff);

    // Batch ALL neighbor gathers up front: 13 independent global_load_dwordx4
    // in flight per wave. Group g handles k = 4*t + g; k>=50 broadcasts lanes
    // 50/51 -> {row 0, weight 0} = harmless dummy.
    float4 e[13];
#pragma unroll
    for (int t = 0; t < 13; ++t) {
        const int nb = __shfl(nbv, 4 * t + g);
        e[t] = *(const float4*)(embsb + (unsigned)nb * 256u + goff);
    }
    float wk[13];
#pragma unroll
    for (int t = 0; t < 13; ++t) {
        wk[t] = __shfl(wv, 4 * t + g);
    }

    const float pos_logit = red16(dot4(u4, p4));
    const float neg_logit = red16(dot4(u4, n4));

    float li = 0.0f;
#pragma unroll
    for (int t = 0; t < 13; ++t) {
        const float d = red16(dot4(u4, e[t]));
        li += -log_sigmoid(d) * wk[t];
    }
    li += __shfl_xor(li, 16);
    li += __shfl_xor(li, 32);

    const float pb = pos_beta[i];
    const float nb = neg_beta[i];
    const float contrib = 2.5f * li
                        - (1.0f + pb) * log_sigmoid(pos_logit)
                        - (1.0f + nb) * log_sigmoid(-neg_logit);

    __shared__ float s[4];
    if (lane == 0) s[wave] = contrib;
    __syncthreads();
    if (tid == 0) {
        partial[blockIdx.x] = s[0] + s[1] + s[2] + s[3];
    }
}

__global__ __launch_bounds__(256) void ultragcn_reduce(
    const float* __restrict__ partial, float* __restrict__ out, int n)
{
    const int tid  = threadIdx.x;
    const int lane = tid & 63;
    const int wave = tid >> 6;

    // n = 4096 = 256 threads * 4 float4
    const float4* p4 = (const float4*)partial;
    float s = 0.0f;
#pragma unroll
    for (int r = 0; r < 4; ++r) {
        float4 v = p4[r * 256 + tid];
        s += (v.x + v.y) + (v.z + v.w);
    }

    s += __shfl_xor(s, 1);
    s += __shfl_xor(s, 2);
    s += __shfl_xor(s, 4);
    s += __shfl_xor(s, 8);
    s += __shfl_xor(s, 16);
    s += __shfl_xor(s, 32);

    __shared__ float ws[4];
    if (lane == 0) ws[wave] = s;
    __syncthreads();
    if (tid == 0) out[0] = ws[0] + ws[1] + ws[2] + ws[3];
}

extern "C" void kernel_launch(void* const* d_in, const int* in_sizes, int n_in,
                              void* d_out, int out_size, void* d_ws, size_t ws_size,
                              hipStream_t stream)
{
    const int*   user     = (const int*)  d_in[0];
    const int*   pos      = (const int*)  d_in[1];
    const int*   neg      = (const int*)  d_in[2];
    const float* pos_beta = (const float*)d_in[3];
    const float* neg_beta = (const float*)d_in[4];
    const float* weights  = (const float*)d_in[5];
    const int*   neighbor = (const int*)  d_in[6];
    const float* embs     = (const float*)d_in[7];

    float* out     = (float*)d_out;
    float* partial = (float*)d_ws;       // 4096 floats = 16 KB scratch

    const int nblocks = BATCH / 4;       // 4096
    ultragcn_main<<<nblocks, 256, 0, stream>>>(
        user, pos, neg, pos_beta, neg_beta, weights, neighbor, embs, partial);
    ultragcn_reduce<<<1, 256, 0, stream>>>(partial, out, nblocks);
}